// Round 9
// baseline (684.224 us; speedup 1.0000x reference)
//
#include <hip/hip_runtime.h>
#include <hip/hip_bf16.h>
#include <cstdint>
#include <cstddef>

// ---------------------------------------------------------------------------
// GCN encoder, bf16-MFMA. CSR via 2-pass stable LSD radix sort (R8 structure).
// R9: XCD-sliced aggregation — feature dim split into 32-feature (64B) column
// stripes; slice = blockIdx.x & 7 pins each stripe to one XCD (blockIdx
// round-robins across XCDs), so the 3.2 MB stripe lives in that XCD's 4 MB L2
// and every gather after cold-fill is an own-L2 hit. 16-lane group per node,
// one 64B line per edge. Sum order per feature unchanged -> bit-identical.
// ---------------------------------------------------------------------------

using frag_ab = __attribute__((ext_vector_type(8))) short;  // 8 bf16
using f32x4   = __attribute__((ext_vector_type(4))) float;
typedef unsigned short u16;

#define NB 1024  // radix partition blocks (contiguous edge ranges)

__device__ __forceinline__ short f2bf(float f) {
    return __builtin_bit_cast(short, __float2bfloat16(f));
}

// ------------------------------- degrees -----------------------------------

__global__ __launch_bounds__(256) void count_kernel(const int* __restrict__ dst, int E,
                                                    int* __restrict__ counts) {
    int i = blockIdx.x * blockDim.x + threadIdx.x;
    int stride = gridDim.x * blockDim.x;
    for (; i < E; i += stride) atomicAdd(&counts[dst[i]], 1);
}

// Single-block scan: counts -> exclusive offsets; also emits dinv (fused).
__global__ __launch_bounds__(1024) void scan_kernel(const int* __restrict__ counts,
                                                    int* __restrict__ offs,
                                                    float* __restrict__ dinv,
                                                    int n, int total) {
    __shared__ int ssum[1024];
    const int tid = threadIdx.x;
    const int chunk = (n + 1023) / 1024;
    const int beg = tid * chunk;
    const int end = min(beg + chunk, n);
    int local = 0;
    for (int i = beg; i < end; ++i) {
        const int c = counts[i];
        dinv[i] = rsqrtf((float)(c + 1));  // +1 self-loop
        local += c;
    }
    ssum[tid] = local;
    __syncthreads();
    for (int off = 1; off < 1024; off <<= 1) {
        int v = (tid >= off) ? ssum[tid - off] : 0;
        __syncthreads();
        ssum[tid] += v;
        __syncthreads();
    }
    int run = ssum[tid] - local;
    for (int i = beg; i < end; ++i) {
        offs[i] = run;
        run += counts[i];
    }
    if (tid == 0) offs[n] = total;
}

// --------------------------- radix sort by dst -----------------------------
// PASS 1: digit = dst & 255, input = (dst[], src[]), output = uint2(dst,src).
// PASS 2: digit = dst >> 8,  input = uint2 recs,     output = csr[] (src only).
// Histogram layout: h[digit * NB + block].

template<int PASS>
__global__ __launch_bounds__(256) void hist_kernel(const void* __restrict__ in,
                                                   int E, int CH,
                                                   int* __restrict__ h) {
    __shared__ int hist[256];
    const int b = blockIdx.x;
    const int t = threadIdx.x;
    hist[t] = 0;
    __syncthreads();
    const int beg = b * CH;
    const int end = min(beg + CH, E);
    if constexpr (PASS == 1) {
        const int* dst = (const int*)in;
        for (int i = beg + t; i < end; i += 256) atomicAdd(&hist[dst[i] & 255], 1);
    } else {
        const uint2* rec = (const uint2*)in;
        for (int i = beg + t; i < end; i += 256) atomicAdd(&hist[(int)(rec[i].x >> 8)], 1);
    }
    __syncthreads();
    h[t * NB + b] = hist[t];  // transposed store
}

// Stage 1: block d scans its row h[d][0..NB) in parallel.
__global__ __launch_bounds__(256) void row_scan_kernel(int* __restrict__ h,
                                                       int* __restrict__ tot) {
    __shared__ int part[256];
    const int d = blockIdx.x;
    const int t = threadIdx.x;
    int* row = h + (size_t)d * NB;
    int4 v = *(int4*)(row + t * 4);
    const int s = v.x + v.y + v.z + v.w;
    part[t] = s;
    __syncthreads();
    for (int o = 1; o < 256; o <<= 1) {
        int u = (t >= o) ? part[t - o] : 0;
        __syncthreads();
        part[t] += u;
        __syncthreads();
    }
    const int ex = part[t] - s;
    int4 o4;
    o4.x = ex;
    o4.y = ex + v.x;
    o4.z = ex + v.x + v.y;
    o4.w = ex + v.x + v.y + v.z;
    *(int4*)(row + t * 4) = o4;
    if (t == 255) tot[d] = part[255];
}

// Stage 2: exclusive scan of 256 digit totals -> digbase.
__global__ __launch_bounds__(256) void digit_scan_kernel(const int* __restrict__ tot,
                                                         int* __restrict__ digbase) {
    __shared__ int s[256];
    const int t = threadIdx.x;
    const int v = tot[t];
    s[t] = v;
    __syncthreads();
    for (int o = 1; o < 256; o <<= 1) {
        int u = (t >= o) ? s[t - o] : 0;
        __syncthreads();
        s[t] += u;
        __syncthreads();
    }
    digbase[t] = s[t] - v;
}

// Stable scatter: ONE wave per block walks its contiguous range in order.
template<int PASS>
__global__ __launch_bounds__(64) void scatter_kernel(const void* __restrict__ in,
                                                     const int* __restrict__ srcv,
                                                     int E, int CH,
                                                     const int* __restrict__ base,
                                                     const int* __restrict__ digbase,
                                                     void* __restrict__ outv) {
    __shared__ int cur[256];
    const int b = blockIdx.x;
    const int lane = threadIdx.x;
    for (int t = lane; t < 256; t += 64) cur[t] = base[t * NB + b] + digbase[t];
    const int beg = b * CH;
    const int end = min(beg + CH, E);
    const unsigned long long below = (1ull << lane) - 1;
    for (int i0 = beg; i0 < end; i0 += 64) {
        const int i = i0 + lane;
        const bool act = i < end;
        int d = 0, s = 0;
        if (act) {
            if constexpr (PASS == 1) {
                d = ((const int*)in)[i];
                s = srcv[i];
            } else {
                uint2 r = ((const uint2*)in)[i];
                d = (int)r.x;
                s = (int)r.y;
            }
        }
        const int dig = (PASS == 1) ? (d & 255) : (d >> 8);
        unsigned long long m = __ballot(act);
#pragma unroll
        for (int bit = 0; bit < 8; ++bit) {
            unsigned long long bb = __ballot((dig >> bit) & 1);
            m &= ((dig >> bit) & 1) ? bb : ~bb;
        }
        if (act) {
            const int rank = __popcll(m & below);
            const int cnt = __popcll(m);
            const int c = cur[dig];
            if (rank == cnt - 1) cur[dig] = c + cnt;
            if constexpr (PASS == 1)
                ((uint2*)outv)[c + rank] = make_uint2((unsigned)d, (unsigned)s);
            else
                ((int*)outv)[c + rank] = s;
        }
    }
}

// --------------------------- weight prep (bf16^T) --------------------------

__global__ __launch_bounds__(256) void prep_w(const float* __restrict__ W,
                                              short* __restrict__ Wt, int K, int N) {
    int i = blockIdx.x * 256 + threadIdx.x;  // over K*N
    if (i >= K * N) return;
    int k = i / N, nn = i - k * N;
    Wt[(size_t)nn * K + k] = f2bf(W[i]);
}

// ------------------------------- MFMA GEMM ---------------------------------
template<int WM, int WN, int NI, bool A_BF16, bool SCALE, bool BIAS, bool OUT_BF16>
__global__ __launch_bounds__(256) void gemm_mfma(const void* __restrict__ Av,
                                                 const short* __restrict__ Bt,
                                                 const float* __restrict__ dinv,
                                                 const float* __restrict__ bias,
                                                 void* __restrict__ Cv,
                                                 int M, int N, int K) {
    constexpr int TM = WM * 64;
    constexpr int TN = WN * NI * 16;
    const int wid = threadIdx.x >> 6;
    const int lane = threadIdx.x & 63;
    const int wm = wid / WN;
    const int wn = wid % WN;
    const int bm = blockIdx.y * TM + wm * 64;
    const int bn = blockIdx.x * TN + wn * NI * 16;
    const int r15 = lane & 15;
    const int g = lane >> 4;

    f32x4 acc[4][NI] = {};

    int arow[4];
#pragma unroll
    for (int mi = 0; mi < 4; ++mi) arow[mi] = min(bm + mi * 16 + r15, M - 1);

    for (int k0 = 0; k0 < K; k0 += 32) {
        const int kb = k0 + g * 8;
        frag_ab af[4];
#pragma unroll
        for (int mi = 0; mi < 4; ++mi) {
            if constexpr (A_BF16) {
                af[mi] = *(const frag_ab*)((const short*)Av + (size_t)arow[mi] * K + kb);
            } else {
                const float* ap = (const float*)Av + (size_t)arow[mi] * K + kb;
                float4 lo = *(const float4*)ap;
                float4 hi = *(const float4*)(ap + 4);
                frag_ab t;
                t[0] = f2bf(lo.x); t[1] = f2bf(lo.y); t[2] = f2bf(lo.z); t[3] = f2bf(lo.w);
                t[4] = f2bf(hi.x); t[5] = f2bf(hi.y); t[6] = f2bf(hi.z); t[7] = f2bf(hi.w);
                af[mi] = t;
            }
        }
        frag_ab bf[NI];
#pragma unroll
        for (int ni = 0; ni < NI; ++ni)
            bf[ni] = *(const frag_ab*)(Bt + (size_t)(bn + ni * 16 + r15) * K + kb);
#pragma unroll
        for (int mi = 0; mi < 4; ++mi)
#pragma unroll
            for (int ni = 0; ni < NI; ++ni)
                acc[mi][ni] = __builtin_amdgcn_mfma_f32_16x16x32_bf16(af[mi], bf[ni],
                                                                      acc[mi][ni], 0, 0, 0);
    }

#pragma unroll
    for (int mi = 0; mi < 4; ++mi) {
#pragma unroll
        for (int j = 0; j < 4; ++j) {
            const int row = bm + mi * 16 + g * 4 + j;
            if (row >= M) continue;
            const float s = SCALE ? dinv[row] : 1.0f;
#pragma unroll
            for (int ni = 0; ni < NI; ++ni) {
                const int col = bn + ni * 16 + r15;
                float v = acc[mi][ni][j] * s;
                if (BIAS) v += bias[col];
                if constexpr (OUT_BF16)
                    ((short*)Cv)[(size_t)row * N + col] = f2bf(v);
                else
                    ((float*)Cv)[(size_t)row * N + col] = v;
            }
        }
    }
}

// ------------------------- XCD-sliced aggregation --------------------------
// out[d] = relu(dinv[d]*(sum_{s in CSR[d]} hs[s] + hs[d]) + b).
// NSL = F/32 column slices of 32 features (64B = 1 line). slice pinned to an
// XCD via blockIdx&7 (round-robin dispatch); stripe = 50000*64B = 3.2MB fits
// the XCD's 4MB L2. 16-lane group per node, 2 bf16 per lane, 4-edge unroll
// with the same add tree as before -> bit-identical sums.
template<int NSL>  // 8 (F=256) or 4 (F=128)
__global__ __launch_bounds__(256) void agg_sliced(const u16* __restrict__ hs,
                                                  const int* __restrict__ csr,
                                                  const int* __restrict__ offs,
                                                  const float* __restrict__ dinv,
                                                  const float* __restrict__ bias,
                                                  u16* __restrict__ out, int n) {
    constexpr int F = NSL * 32;
    constexpr int DUP = 8 / NSL;  // XCDs duplicating each slice (disjoint nodes)
    const int bsl = blockIdx.x & 7;
    const int slice = bsl & (NSL - 1);
    const int node = (blockIdx.x >> 3) * (16 * DUP) + (bsl / NSL) * 16
                   + (threadIdx.x >> 4);
    if (node >= n) return;
    const int r = threadIdx.x & 15;
    const int c0 = slice * 32 + r * 2;
    const u16* hb = hs + c0;

#define LD2(row, A, B)                                                   \
    {                                                                    \
        unsigned u = *(const unsigned*)(hb + (size_t)(row) * F);         \
        A = __builtin_bit_cast(float, u << 16);                          \
        B = __builtin_bit_cast(float, u & 0xffff0000u);                  \
    }

    float s0, s1;
    LD2(node, s0, s1);  // self row (added last, matches reference order)

    float a0 = 0.f, a1 = 0.f;
    int e = offs[node];
    const int end = offs[node + 1];
    for (; e + 4 <= end; e += 4) {
        int i0 = csr[e], i1 = csr[e + 1], i2 = csr[e + 2], i3 = csr[e + 3];
        float t00, t01, t10, t11, t20, t21, t30, t31;
        LD2(i0, t00, t01);
        LD2(i1, t10, t11);
        LD2(i2, t20, t21);
        LD2(i3, t30, t31);
        a0 += ((t00 + t10) + (t20 + t30));
        a1 += ((t01 + t11) + (t21 + t31));
    }
    for (; e < end; ++e) {
        float t0, t1;
        LD2(csr[e], t0, t1);
        a0 += t0;
        a1 += t1;
    }
#undef LD2

    const float di = dinv[node];
    float v0 = fmaf(a0 + s0, di, bias[c0]);
    float v1 = fmaf(a1 + s1, di, bias[c0 + 1]);
    unsigned o = (unsigned)(u16)f2bf(fmaxf(v0, 0.f)) |
                 ((unsigned)(u16)f2bf(fmaxf(v1, 0.f)) << 16);
    *(unsigned*)(out + (size_t)node * F + c0) = o;
}

// ---------------------------------------------------------------------------

extern "C" void kernel_launch(void* const* d_in, const int* in_sizes, int n_in,
                              void* d_out, int out_size, void* d_ws, size_t ws_size,
                              hipStream_t stream) {
    const float* x  = (const float*)d_in[0];
    const int*   ei = (const int*)d_in[1];
    const float* W1 = (const float*)d_in[2];
    const float* b1 = (const float*)d_in[3];
    const float* W2 = (const float*)d_in[4];
    const float* b2 = (const float*)d_in[5];
    const float* Wl = (const float*)d_in[6];
    const float* bl = (const float*)d_in[7];

    const int E = in_sizes[1] / 2;    // 1,600,000
    const int n = in_sizes[0] / 256;  // 50,000
    const int* src = ei;
    const int* dst = ei + E;
    const int CH = (E + NB - 1) / NB;

    char* ws = (char*)d_ws;
    size_t off = 0;
    auto alloc = [&](size_t bytes) -> void* {
        void* p = ws + off;
        off += (bytes + 255) & ~(size_t)255;
        return p;
    };
    short* h      = (short*)alloc((size_t)n * 256 * 2);   // bf16 h1 / h2
    short* a      = (short*)alloc((size_t)n * 256 * 2);   // bf16 a1 / a2
    int*   counts = (int*)alloc((size_t)n * 4);
    int*   offs   = (int*)alloc((size_t)(n + 1) * 4);
    float* dinv   = (float*)alloc((size_t)n * 4);
    int*   csr    = (int*)alloc((size_t)E * 4);
    int*   h1     = (int*)alloc((size_t)NB * 256 * 4);
    int*   h2     = (int*)alloc((size_t)NB * 256 * 4);
    int*   tot1   = (int*)alloc(256 * 4);
    int*   tot2   = (int*)alloc(256 * 4);
    int*   db1    = (int*)alloc(256 * 4);
    int*   db2    = (int*)alloc(256 * 4);
    short* wt1    = (short*)alloc((size_t)256 * 256 * 2);
    short* wt2    = (short*)alloc((size_t)128 * 256 * 2);
    short* wtl    = (short*)alloc((size_t)64 * 128 * 2);
    // rec1 (12.8 MB) aliases 'a' (25.6 MB): CSR build completes before 'a' is used.
    uint2* rec1   = (uint2*)a;
    (void)ws_size;

    hipMemsetAsync(counts, 0, (size_t)n * 4, stream);
    prep_w<<<(256 * 256 + 255) / 256, 256, 0, stream>>>(W1, wt1, 256, 256);
    prep_w<<<(256 * 128 + 255) / 256, 256, 0, stream>>>(W2, wt2, 256, 128);
    prep_w<<<(128 * 64 + 255) / 256, 256, 0, stream>>>(Wl, wtl, 128, 64);

    count_kernel<<<1024, 256, 0, stream>>>(dst, E, counts);
    scan_kernel<<<1, 1024, 0, stream>>>(counts, offs, dinv, n, E);

    // Stable radix sort by dst: pass 1 (low byte) then pass 2 (high byte).
    hist_kernel<1><<<NB, 256, 0, stream>>>(dst, E, CH, h1);
    row_scan_kernel<<<256, 256, 0, stream>>>(h1, tot1);
    digit_scan_kernel<<<1, 256, 0, stream>>>(tot1, db1);
    scatter_kernel<1><<<NB, 64, 0, stream>>>(dst, src, E, CH, h1, db1, rec1);
    hist_kernel<2><<<NB, 256, 0, stream>>>(rec1, E, CH, h2);
    row_scan_kernel<<<256, 256, 0, stream>>>(h2, tot2);
    digit_scan_kernel<<<1, 256, 0, stream>>>(tot2, db2);
    scatter_kernel<2><<<NB, 64, 0, stream>>>(rec1, nullptr, E, CH, h2, db2, csr);

    // Layer 1: h = (x @ W1) * dinv[row]  [bf16]; a = relu(agg(h) + b1) [bf16]
    gemm_mfma<2, 2, 4, false, true, false, true>
        <<<dim3(2, (n + 127) / 128), 256, 0, stream>>>(x, wt1, dinv, nullptr, h, n, 256, 256);
    agg_sliced<8><<<8 * ((n + 15) / 16), 256, 0, stream>>>((const u16*)h, csr, offs,
                                                           dinv, b1, (u16*)a, n);

    // Layer 2: h = (a @ W2) * dinv[row] [bf16]; a = relu(agg(h) + b2) [bf16]
    gemm_mfma<1, 4, 2, true, true, false, true>
        <<<dim3(1, (n + 63) / 64), 256, 0, stream>>>(a, wt2, dinv, nullptr, h, n, 128, 256);
    agg_sliced<4><<<8 * ((n + 31) / 32), 256, 0, stream>>>((const u16*)h, csr, offs,
                                                           dinv, b2, (u16*)a, n);

    // Head: out = a @ Wl + bl  [fp32]
    gemm_mfma<1, 4, 1, true, false, true, false>
        <<<dim3(1, (n + 63) / 64), 256, 0, stream>>>(a, wtl, nullptr, bl, d_out, n, 64, 128);
}